// Round 6
// baseline (394.010 us; speedup 1.0000x reference)
//
#include <hip/hip_runtime.h>
#include <hip/hip_bf16.h>
#include <cstdint>
#include <cstddef>

#define D_MODEL   1024
#define NUM_HEADS 16
#define HEAD_DIM  64
#define SEQ       2048
#define BATCH     4
#define BH        (BATCH*NUM_HEADS)   // 64
#define MROWS     (BATCH*SEQ)         // 8192

typedef _Float16 half8  __attribute__((ext_vector_type(8)));
typedef _Float16 half4v __attribute__((ext_vector_type(4)));
typedef float    floatx4 __attribute__((ext_vector_type(4)));

// ---------------------------------------------------------------------------
// async global -> LDS, 16 bytes per lane. LDS base must be wave-uniform;
// HW writes lds_base + lane*16 (LDS side contiguous; global side per-lane).
// ---------------------------------------------------------------------------
__device__ inline void gld_lds16(const void* g, void* l) {
    __builtin_amdgcn_global_load_lds(
        (__attribute__((address_space(1))) void*)g,
        (__attribute__((address_space(3))) void*)l,
        16, 0, 0);
}

// ---------------------------------------------------------------------------
// RoPE cos/sin table [s][p], p in [0,32): angle = s * 10000^(-p/32), fp64.
// ---------------------------------------------------------------------------
__global__ void rope_table(float2* __restrict__ tab) {
    const int i = blockIdx.x * blockDim.x + threadIdx.x;   // SEQ*32
    const int p = i & 31, s = i >> 5;
    const double inv = pow(10000.0, -(double)p / 32.0);
    const double ang = (double)s * inv;
    tab[i] = make_float2((float)cos(ang), (float)sin(ang));
}

// ---------------------------------------------------------------------------
// fp32 -> split f16 (hi + lo residual) for x, 4-wide. v ~= hi + lo to ~2^-22.
// ---------------------------------------------------------------------------
__global__ void f32_split_f16(const float* __restrict__ in,
                              _Float16* __restrict__ hi,
                              _Float16* __restrict__ lo, int n4) {
    int i = blockIdx.x * blockDim.x + threadIdx.x;
    if (i >= n4) return;
    float4 v = ((const float4*)in)[i];
    half4v h = { (_Float16)v.x, (_Float16)v.y, (_Float16)v.z, (_Float16)v.w };
    half4v l = { (_Float16)(v.x - (float)h.x), (_Float16)(v.y - (float)h.y),
                 (_Float16)(v.z - (float)h.z), (_Float16)(v.w - (float)h.w) };
    ((half4v*)hi)[i] = h;
    ((half4v*)lo)[i] = l;
}

// ---------------------------------------------------------------------------
// All 4 weight converts in one dispatch: qw,kw -> split hi/lo; vw,ow -> hi.
// i indexes 4 * (1024*1024/4) float4 groups.
// ---------------------------------------------------------------------------
__global__ void conv_weights(const float* __restrict__ qw, const float* __restrict__ kw,
                             const float* __restrict__ vw, const float* __restrict__ ow,
                             _Float16* __restrict__ qwh, _Float16* __restrict__ qwl,
                             _Float16* __restrict__ kwh, _Float16* __restrict__ kwl,
                             _Float16* __restrict__ vwh, _Float16* __restrict__ owh) {
    const int i = blockIdx.x * blockDim.x + threadIdx.x;
    const int which = i >> 18;              // 262144 float4 per tensor
    const int j = i & 262143;
    const float4 v = ((const float4*)(which == 0 ? qw : which == 1 ? kw :
                                      which == 2 ? vw : ow))[j];
    half4v h = { (_Float16)v.x, (_Float16)v.y, (_Float16)v.z, (_Float16)v.w };
    if (which < 2) {
        half4v l = { (_Float16)(v.x - (float)h.x), (_Float16)(v.y - (float)h.y),
                     (_Float16)(v.z - (float)h.z), (_Float16)(v.w - (float)h.w) };
        ((half4v*)(which ? kwh : qwh))[j] = h;
        ((half4v*)(which ? kwl : qwl))[j] = l;
    } else {
        ((half4v*)(which == 2 ? vwh : owh))[j] = h;
    }
}

// ---------------------------------------------------------------------------
// Plain GEMM (m97 structure): C[m,n] = sum_k A[m,k]*B[n,k], fp32 out (MODE 0).
// Used for the output projection only.
// ---------------------------------------------------------------------------
__global__ __launch_bounds__(256)
void gemm_bt(const _Float16* __restrict__ A, const _Float16* __restrict__ B,
             float* __restrict__ Cout, int M, int N, int K) {
    __shared__ _Float16 As[128*32];
    __shared__ _Float16 Bs[128*32];

    const int nb = N >> 7;
    const int bx = blockIdx.x % nb;
    const int by = blockIdx.x / nb;
    const int m0 = by << 7, n0 = bx << 7;

    const int t    = threadIdx.x;
    const int w    = t >> 6;
    const int lane = t & 63;
    const int r    = lane & 15;
    const int quad = lane >> 4;
    const int wm   = (w >> 1) << 6;
    const int wn   = (w & 1) << 6;

    const int srow = lane >> 2;
    const int scol = (lane & 3) << 3;

    floatx4 acc[4][4];
    #pragma unroll
    for (int i = 0; i < 4; i++)
        #pragma unroll
        for (int j = 0; j < 4; j++)
            acc[i][j] = (floatx4){0.f, 0.f, 0.f, 0.f};

    for (int k0 = 0; k0 < K; k0 += 32) {
        __syncthreads();
        #pragma unroll
        for (int p = 0; p < 2; ++p) {
            const int rbase = p*64 + w*16;
            gld_lds16(&A[(size_t)(m0 + rbase + srow)*K + k0 + scol], &As[rbase*32]);
            gld_lds16(&B[(size_t)(n0 + rbase + srow)*K + k0 + scol], &Bs[rbase*32]);
        }
        __syncthreads();

        half8 af[4], bf[4];
        #pragma unroll
        for (int i = 0; i < 4; i++)
            af[i] = *(const half8*)&As[(wm + i*16 + r)*32 + quad*8];
        #pragma unroll
        for (int j = 0; j < 4; j++)
            bf[j] = *(const half8*)&Bs[(wn + j*16 + r)*32 + quad*8];

        #pragma unroll
        for (int i = 0; i < 4; i++)
            #pragma unroll
            for (int j = 0; j < 4; j++)
                acc[i][j] = __builtin_amdgcn_mfma_f32_16x16x32_f16(
                                af[i], bf[j], acc[i][j], 0, 0, 0);
    }

    #pragma unroll
    for (int i = 0; i < 4; i++)
        #pragma unroll
        for (int j = 0; j < 4; j++)
            #pragma unroll
            for (int v = 0; v < 4; v++) {
                const int m = m0 + wm + i*16 + quad*4 + v;
                const int n = n0 + wn + j*16 + r;
                Cout[(size_t)m*N + n] = acc[i][j][v];
            }
}

// ---------------------------------------------------------------------------
// Fused Q/K/V projection. Grid = 64 m-tiles x 24 n-tiles (wt = n-tile>>3).
// wt 0/1 (Q/K): 3-chain split GEMM (Ah·Bh + Ah·Bl + Al·Bh), RoPE epilogue,
//              split hi/lo f16 head-split output [b][h][s][64].
// wt 2   (V):  1-chain hi GEMM, head-split-T output [b][h][d][s].
// Block-uniform branches; 6 blocks/CU dispatched for barrier-drain overlap.
// ---------------------------------------------------------------------------
__global__ __launch_bounds__(256)
void gemm_qkv(const _Float16* __restrict__ Axh, const _Float16* __restrict__ Axl,
              const _Float16* __restrict__ qwh, const _Float16* __restrict__ qwl,
              const _Float16* __restrict__ kwh, const _Float16* __restrict__ kwl,
              const _Float16* __restrict__ vwh,
              _Float16* __restrict__ Qhi, _Float16* __restrict__ Qlo,
              _Float16* __restrict__ Khi, _Float16* __restrict__ Klo,
              _Float16* __restrict__ Vt,  const float2* __restrict__ tab) {
    __shared__ _Float16 Ash[128*32];
    __shared__ _Float16 Asl[128*32];
    __shared__ _Float16 Bsh[128*32];
    __shared__ _Float16 Bsl[128*32];

    const int bxa = blockIdx.x;
    const int bx  = bxa % 24;
    const int by  = bxa / 24;
    const int wt  = bx >> 3;               // 0=Q, 1=K, 2=V
    const int n0  = (bx & 7) << 7;         // within this weight's 1024 cols
    const int m0  = by << 7;

    const _Float16* Bh = (wt == 0) ? qwh : (wt == 1) ? kwh : vwh;
    const _Float16* Bl = (wt == 0) ? qwl : kwl;      // unused when wt==2

    const int t    = threadIdx.x;
    const int w    = t >> 6;
    const int lane = t & 63;
    const int r    = lane & 15;
    const int quad = lane >> 4;
    const int wm   = (w >> 1) << 6;
    const int wn   = (w & 1) << 6;

    const int srow = lane >> 2;
    const int scol = (lane & 3) << 3;

    floatx4 acc[4][4];
    #pragma unroll
    for (int i = 0; i < 4; i++)
        #pragma unroll
        for (int j = 0; j < 4; j++)
            acc[i][j] = (floatx4){0.f, 0.f, 0.f, 0.f};

    for (int k0 = 0; k0 < 1024; k0 += 32) {
        __syncthreads();
        #pragma unroll
        for (int p = 0; p < 2; ++p) {
            const int rbase = p*64 + w*16;
            const size_t ga = (size_t)(m0 + rbase + srow)*1024 + k0 + scol;
            const size_t gb = (size_t)(n0 + rbase + srow)*1024 + k0 + scol;
            gld_lds16(&Axh[ga], &Ash[rbase*32]);
            gld_lds16(&Bh [gb], &Bsh[rbase*32]);
            if (wt < 2) {
                gld_lds16(&Axl[ga], &Asl[rbase*32]);
                gld_lds16(&Bl [gb], &Bsl[rbase*32]);
            }
        }
        __syncthreads();

        half8 ah[4], bh[4];
        #pragma unroll
        for (int i = 0; i < 4; i++)
            ah[i] = *(const half8*)&Ash[(wm + i*16 + r)*32 + quad*8];
        #pragma unroll
        for (int j = 0; j < 4; j++)
            bh[j] = *(const half8*)&Bsh[(wn + j*16 + r)*32 + quad*8];

        if (wt < 2) {
            half8 al[4], bl[4];
            #pragma unroll
            for (int i = 0; i < 4; i++)
                al[i] = *(const half8*)&Asl[(wm + i*16 + r)*32 + quad*8];
            #pragma unroll
            for (int j = 0; j < 4; j++)
                bl[j] = *(const half8*)&Bsl[(wn + j*16 + r)*32 + quad*8];
            #pragma unroll
            for (int i = 0; i < 4; i++)
                #pragma unroll
                for (int j = 0; j < 4; j++) {
                    acc[i][j] = __builtin_amdgcn_mfma_f32_16x16x32_f16(
                                    ah[i], bh[j], acc[i][j], 0, 0, 0);
                    acc[i][j] = __builtin_amdgcn_mfma_f32_16x16x32_f16(
                                    ah[i], bl[j], acc[i][j], 0, 0, 0);
                    acc[i][j] = __builtin_amdgcn_mfma_f32_16x16x32_f16(
                                    al[i], bh[j], acc[i][j], 0, 0, 0);
                }
        } else {
            #pragma unroll
            for (int i = 0; i < 4; i++)
                #pragma unroll
                for (int j = 0; j < 4; j++)
                    acc[i][j] = __builtin_amdgcn_mfma_f32_16x16x32_f16(
                                    ah[i], bh[j], acc[i][j], 0, 0, 0);
        }
    }

    // Epilogue — C/D layout: col = lane&15, row = quad*4 + reg
    if (wt < 2) {
        _Float16* Chi = wt ? Khi : Qhi;
        _Float16* Clo = wt ? Klo : Qlo;
        #pragma unroll
        for (int i = 0; i < 4; i++) {
            #pragma unroll
            for (int v = 0; v < 4; v++) {
                const int m  = m0 + wm + i*16 + quad*4 + v;
                const int b  = m >> 11;
                const int s_ = m & 2047;
                #pragma unroll
                for (int j = 0; j < 4; j++) {
                    const int n = n0 + wn + j*16 + r;
                    const int h = n >> 6, d = n & 63;
                    const float val = acc[i][j][v];
                    const float pv  = __shfl_xor(val, 1);
                    const float2 cs = tab[s_*32 + (d >> 1)];
                    const float res = (r & 1) ? (pv*cs.y + val*cs.x)
                                              : (val*cs.x - pv*cs.y);
                    const size_t idx = ((((size_t)b*NUM_HEADS + h)*SEQ + s_) << 6) + d;
                    const _Float16 hv = (_Float16)res;
                    Chi[idx] = hv;
                    Clo[idx] = (_Float16)(res - (float)hv);
                }
            }
        }
    } else {
        #pragma unroll
        for (int i = 0; i < 4; i++) {
            #pragma unroll
            for (int v = 0; v < 4; v++) {
                const int m  = m0 + wm + i*16 + quad*4 + v;
                const int b  = m >> 11;
                const int s_ = m & 2047;
                #pragma unroll
                for (int j = 0; j < 4; j++) {
                    const int n = n0 + wn + j*16 + r;
                    const int h = n >> 6, d = n & 63;
                    Vt[((((size_t)b*NUM_HEADS + h)*HEAD_DIM + d) << 11) + s_]
                        = (_Float16)acc[i][j][v];
                }
            }
        }
    }
}

// ---------------------------------------------------------------------------
// Causal flash attention, block-cooperative, transposed scores.
// 512 threads = 8 waves; block handles 128 Q-rows (wave w: rows q0+w*16..+15).
// 64-key iterations; K hi/lo and V^T staged as 64x32 half-tiles (64B LDS rows
// -> contiguous-1024B ds_read_b128, m97 shape, conflict-minimal).
// Staging split: 24 strips (6 planes x 4) over 8 waves x 3 gld each.
// S^T = K·Q^T (q in lane&15 -> softmax reductions are 2 shuffles).
// O^T = V^T·P (q in lane&15 -> alpha rescale shuffle-free).
// Fully-masked tiles: compute skipped by wave-uniform guard (barriers kept).
// Longest blocks launch first (LPT).
// ---------------------------------------------------------------------------
#define PSTR 72   // P strip stride in f16
__global__ __launch_bounds__(512)
void flash_attn(const _Float16* __restrict__ Qhi, const _Float16* __restrict__ Qlo,
                const _Float16* __restrict__ Khi, const _Float16* __restrict__ Klo,
                const _Float16* __restrict__ Vt,  _Float16* __restrict__ AO) {
    __shared__ _Float16 Ksh0[64*32];   // K hi, d [0,32)
    __shared__ _Float16 Ksh1[64*32];   // K hi, d [32,64)
    __shared__ _Float16 Ksl0[64*32];   // K lo, d [0,32)
    __shared__ _Float16 Ksl1[64*32];   // K lo, d [32,64)
    __shared__ _Float16 Vs0 [64*32];   // V^T, keys [0,32)
    __shared__ _Float16 Vs1 [64*32];   // V^T, keys [32,64)
    __shared__ _Float16 Pl  [8][16*PSTR];

    const int t    = threadIdx.x;
    const int w    = t >> 6;               // 0..7
    const int lane = t & 63;
    const int r    = lane & 15;
    const int quad = lane >> 4;

    const int bx = blockIdx.x;
    const int bh = bx & 63;                 // 64 bh, fastest
    const int qb = 15 - (bx >> 6);          // 16 q-blocks of 128, longest first
    const int q0w = qb*128 + w*16;
    const int b  = bh >> 4, h = bh & 15;

    const _Float16* Qh_ = Qhi + (size_t)bh * SEQ * HEAD_DIM;
    const _Float16* Ql_ = Qlo + (size_t)bh * SEQ * HEAD_DIM;
    const _Float16* Khg = Khi + (size_t)bh * SEQ * HEAD_DIM;
    const _Float16* Klg = Klo + (size_t)bh * SEQ * HEAD_DIM;
    const _Float16* Vtg = Vt  + (size_t)bh * HEAD_DIM * SEQ;

    // Q B-fragments: B[n=q=r][k=d=c*32+quad*8+j], hi and lo
    half8 qh[2], ql[2];
    #pragma unroll
    for (int c = 0; c < 2; ++c) {
        qh[c] = *(const half8*)&Qh_[(size_t)(q0w + r)*64 + c*32 + quad*8];
        ql[c] = *(const half8*)&Ql_[(size_t)(q0w + r)*64 + c*32 + quad*8];
    }

    // O^T accumulators: tile d = dt*16+quad*4+v, col q = r
    floatx4 ot[4];
    #pragma unroll
    for (int dt = 0; dt < 4; ++dt) ot[dt] = (floatx4){0.f,0.f,0.f,0.f};
    float mi = -1e30f, li = 0.f;

    const int sr = lane >> 2;             // staging: 16 rows per strip
    const int sc = (lane & 3) << 3;

    const int niter = 2*qb + 2;
    for (int kt = 0; kt < niter; ++kt) {
        const int k0 = kt << 6;

        __syncthreads();                  // prior iter's LDS reads complete
        #pragma unroll
        for (int i = 0; i < 3; ++i) {     // 24 strips over 8 waves
            const int strip = w + (i << 3);        // wave-uniform
            const int plane = strip >> 2;
            const int rb    = (strip & 3) << 4;
            const int row   = rb + sr;
            switch (plane) {
            case 0: gld_lds16(&Khg[(size_t)(k0 + row)*64 +      sc], &Ksh0[rb*32]); break;
            case 1: gld_lds16(&Khg[(size_t)(k0 + row)*64 + 32 + sc], &Ksh1[rb*32]); break;
            case 2: gld_lds16(&Klg[(size_t)(k0 + row)*64 +      sc], &Ksl0[rb*32]); break;
            case 3: gld_lds16(&Klg[(size_t)(k0 + row)*64 + 32 + sc], &Ksl1[rb*32]); break;
            case 4: gld_lds16(&Vtg[(size_t)row*SEQ + k0 +       sc], &Vs0 [rb*32]); break;
            case 5: gld_lds16(&Vtg[(size_t)row*SEQ + k0 + 32 +  sc], &Vs1 [rb*32]); break;
            }
        }
        __syncthreads();                  // vmcnt(0): staging complete

        if (k0 > q0w + 15) continue;      // fully-masked for this wave (uniform)

        // S^T = K·Q^T : 16 scores per lane (key = sub*16+quad*4+v, q = r)
        float s[16];
        #pragma unroll
        for (int sub = 0; sub < 4; ++sub) {
            floatx4 a = (floatx4){0.f,0.f,0.f,0.f};
            const int fr = (sub*16 + r)*32 + quad*8;   // contiguous 1024B/read
            const half8 kh0 = *(const half8*)&Ksh0[fr];
            const half8 kh1 = *(const half8*)&Ksh1[fr];
            const half8 kl0 = *(const half8*)&Ksl0[fr];
            const half8 kl1 = *(const half8*)&Ksl1[fr];
            a = __builtin_amdgcn_mfma_f32_16x16x32_f16(kh0, qh[0], a, 0, 0, 0);
            a = __builtin_amdgcn_mfma_f32_16x16x32_f16(kh1, qh[1], a, 0, 0, 0);
            a = __builtin_amdgcn_mfma_f32_16x16x32_f16(kh0, ql[0], a, 0, 0, 0);
            a = __builtin_amdgcn_mfma_f32_16x16x32_f16(kh1, ql[1], a, 0, 0, 0);
            a = __builtin_amdgcn_mfma_f32_16x16x32_f16(kl0, qh[0], a, 0, 0, 0);
            a = __builtin_amdgcn_mfma_f32_16x16x32_f16(kl1, qh[1], a, 0, 0, 0);
            #pragma unroll
            for (int v = 0; v < 4; ++v) s[sub*4 + v] = a[v] * 0.125f;
        }

        if (k0 + 63 > q0w) {              // partial tile: causal mask (uniform test)
            #pragma unroll
            for (int sub = 0; sub < 4; ++sub)
                #pragma unroll
                for (int v = 0; v < 4; ++v)
                    if (k0 + sub*16 + quad*4 + v > q0w + r)
                        s[sub*4 + v] = -1e30f;
        }

        // online softmax over this tile's 64 keys (per lane: q = r)
        float tm = s[0];
        #pragma unroll
        for (int i = 1; i < 16; ++i) tm = fmaxf(tm, s[i]);
        tm = fmaxf(tm, __shfl_xor(tm, 16));
        tm = fmaxf(tm, __shfl_xor(tm, 32));
        const float mn = fmaxf(mi, tm);
        const float alpha = __expf(mi - mn);
        mi = mn;
        float rs = 0.f;
        #pragma unroll
        for (int i = 0; i < 16; ++i) { s[i] = __expf(s[i] - mn); rs += s[i]; }
        rs += __shfl_xor(rs, 16);
        rs += __shfl_xor(rs, 32);
        li = li*alpha + rs;
        #pragma unroll
        for (int dt = 0; dt < 4; ++dt)
            #pragma unroll
            for (int v = 0; v < 4; ++v) ot[dt][v] *= alpha;

        // P^T -> per-wave LDS strip [q=r][key], packed 4-wide
        #pragma unroll
        for (int sub = 0; sub < 4; ++sub) {
            half4v pk = { (_Float16)s[sub*4+0], (_Float16)s[sub*4+1],
                          (_Float16)s[sub*4+2], (_Float16)s[sub*4+3] };
            *(half4v*)&Pl[w][r*PSTR + sub*16 + quad*4] = pk;
        }
        // (same-wave write->read: compiler inserts lgkmcnt wait, no barrier)

        // O^T += V^T·P : A = V^T-frag [m=d][k=key], B = P [n=q][k=key]
        #pragma unroll
        for (int c = 0; c < 2; ++c) {
            const half8 pf = *(const half8*)&Pl[w][r*PSTR + c*32 + quad*8];
            const _Float16* Vsc = c ? Vs1 : Vs0;
            #pragma unroll
            for (int dt = 0; dt < 4; ++dt) {
                const half8 vf = *(const half8*)&Vsc[(dt*16 + r)*32 + quad*8];
                ot[dt] = __builtin_amdgcn_mfma_f32_16x16x32_f16(vf, pf, ot[dt], 0, 0, 0);
            }
        }
    }

    // epilogue: normalize, write AO [b][s=q][h*64 + d] (8B stores)
    const float inv = 1.0f / li;
    const int q = q0w + r;
    #pragma unroll
    for (int dt = 0; dt < 4; ++dt) {
        half4v o = { (_Float16)(ot[dt][0]*inv), (_Float16)(ot[dt][1]*inv),
                     (_Float16)(ot[dt][2]*inv), (_Float16)(ot[dt][3]*inv) };
        *(half4v*)&AO[((size_t)(b*SEQ + q))*D_MODEL + h*HEAD_DIM + dt*16 + quad*4] = o;
    }
}

// ---------------------------------------------------------------------------
extern "C" void kernel_launch(void* const* d_in, const int* in_sizes, int n_in,
                              void* d_out, int out_size, void* d_ws, size_t ws_size,
                              hipStream_t stream) {
    const float* x  = (const float*)d_in[0];
    const float* qw = (const float*)d_in[1];
    const float* kw = (const float*)d_in[2];
    const float* vw = (const float*)d_in[3];
    const float* ow = (const float*)d_in[4];
    float* out = (float*)d_out;

    // workspace layout (_Float16 counts), total ~147.3 MB
    _Float16* xh  = (_Float16*)d_ws;
    _Float16* xl  = xh  + (size_t)MROWS * D_MODEL;
    _Float16* qwh = xl  + (size_t)MROWS * D_MODEL;
    _Float16* qwl = qwh + (size_t)D_MODEL * D_MODEL;
    _Float16* kwh = qwl + (size_t)D_MODEL * D_MODEL;
    _Float16* kwl = kwh + (size_t)D_MODEL * D_MODEL;
    _Float16* vwh = kwl + (size_t)D_MODEL * D_MODEL;
    _Float16* owh = vwh + (size_t)D_MODEL * D_MODEL;
    _Float16* Qhi = owh + (size_t)D_MODEL * D_MODEL;
    _Float16* Qlo = Qhi + (size_t)MROWS * D_MODEL;
    _Float16* Khi = Qlo + (size_t)MROWS * D_MODEL;
    _Float16* Klo = Khi + (size_t)MROWS * D_MODEL;
    _Float16* Vt  = Klo + (size_t)MROWS * D_MODEL;
    _Float16* AO  = Vt  + (size_t)MROWS * D_MODEL;
    float2*   tab = (float2*)(AO + (size_t)MROWS * D_MODEL);

    rope_table<<<(SEQ*32)/256, 256, 0, stream>>>(tab);

    const int nx4 = MROWS * D_MODEL / 4;
    f32_split_f16<<<nx4/256, 256, 0, stream>>>(x, xh, xl, nx4);
    conv_weights<<<(4*262144)/256, 256, 0, stream>>>(qw, kw, vw, ow,
                                                     qwh, qwl, kwh, kwl, vwh, owh);

    gemm_qkv<<<64*24, 256, 0, stream>>>(xh, xl, qwh, qwl, kwh, kwl, vwh,
                                        Qhi, Qlo, Khi, Klo, Vt, tab);

    flash_attn<<<BH * (SEQ/128), 512, 0, stream>>>(Qhi, Qlo, Khi, Klo, Vt, AO);

    gemm_bt<<<(MROWS/128)*(D_MODEL/128), 256, 0, stream>>>(AO, owh, out,
                                                           MROWS, D_MODEL, D_MODEL);
}

// Round 7
// 378.982 us; speedup vs baseline: 1.0397x; 1.0397x over previous
//
#include <hip/hip_runtime.h>
#include <hip/hip_bf16.h>
#include <cstdint>
#include <cstddef>

#define D_MODEL   1024
#define NUM_HEADS 16
#define HEAD_DIM  64
#define SEQ       2048
#define BATCH     4
#define BH        (BATCH*NUM_HEADS)   // 64
#define MROWS     (BATCH*SEQ)         // 8192

typedef _Float16 half8  __attribute__((ext_vector_type(8)));
typedef _Float16 half4v __attribute__((ext_vector_type(4)));
typedef float    floatx4 __attribute__((ext_vector_type(4)));

// ---------------------------------------------------------------------------
// async global -> LDS, 16 bytes per lane. LDS base must be wave-uniform;
// HW writes lds_base + lane*16 (LDS side contiguous; global side per-lane).
// ---------------------------------------------------------------------------
__device__ inline void gld_lds16(const void* g, void* l) {
    __builtin_amdgcn_global_load_lds(
        (__attribute__((address_space(1))) void*)g,
        (__attribute__((address_space(3))) void*)l,
        16, 0, 0);
}

// ---------------------------------------------------------------------------
// RoPE cos/sin table [s][p], p in [0,32): angle = s * 10000^(-p/32), fp64.
// ---------------------------------------------------------------------------
__global__ void rope_table(float2* __restrict__ tab) {
    const int i = blockIdx.x * blockDim.x + threadIdx.x;   // SEQ*32
    const int p = i & 31, s = i >> 5;
    const double inv = pow(10000.0, -(double)p / 32.0);
    const double ang = (double)s * inv;
    tab[i] = make_float2((float)cos(ang), (float)sin(ang));
}

// ---------------------------------------------------------------------------
// fp32 -> split f16 (hi + lo residual) for x, 4-wide. v ~= hi + lo to ~2^-22.
// ---------------------------------------------------------------------------
__global__ void f32_split_f16(const float* __restrict__ in,
                              _Float16* __restrict__ hi,
                              _Float16* __restrict__ lo, int n4) {
    int i = blockIdx.x * blockDim.x + threadIdx.x;
    if (i >= n4) return;
    float4 v = ((const float4*)in)[i];
    half4v h = { (_Float16)v.x, (_Float16)v.y, (_Float16)v.z, (_Float16)v.w };
    half4v l = { (_Float16)(v.x - (float)h.x), (_Float16)(v.y - (float)h.y),
                 (_Float16)(v.z - (float)h.z), (_Float16)(v.w - (float)h.w) };
    ((half4v*)hi)[i] = h;
    ((half4v*)lo)[i] = l;
}

// ---------------------------------------------------------------------------
// All 4 weight converts in one dispatch: qw,kw -> split hi/lo; vw,ow -> hi.
// ---------------------------------------------------------------------------
__global__ void conv_weights(const float* __restrict__ qw, const float* __restrict__ kw,
                             const float* __restrict__ vw, const float* __restrict__ ow,
                             _Float16* __restrict__ qwh, _Float16* __restrict__ qwl,
                             _Float16* __restrict__ kwh, _Float16* __restrict__ kwl,
                             _Float16* __restrict__ vwh, _Float16* __restrict__ owh) {
    const int i = blockIdx.x * blockDim.x + threadIdx.x;
    const int which = i >> 18;              // 262144 float4 per tensor
    const int j = i & 262143;
    const float4 v = ((const float4*)(which == 0 ? qw : which == 1 ? kw :
                                      which == 2 ? vw : ow))[j];
    half4v h = { (_Float16)v.x, (_Float16)v.y, (_Float16)v.z, (_Float16)v.w };
    if (which < 2) {
        half4v l = { (_Float16)(v.x - (float)h.x), (_Float16)(v.y - (float)h.y),
                     (_Float16)(v.z - (float)h.z), (_Float16)(v.w - (float)h.w) };
        ((half4v*)(which ? kwh : qwh))[j] = h;
        ((half4v*)(which ? kwl : qwl))[j] = l;
    } else {
        ((half4v*)(which == 2 ? vwh : owh))[j] = h;
    }
}

// ---------------------------------------------------------------------------
// Plain GEMM (m97 structure): C[m,n] = sum_k A[m,k]*B[n,k], fp32 out.
// Used for the output projection only.
// ---------------------------------------------------------------------------
__global__ __launch_bounds__(256)
void gemm_bt(const _Float16* __restrict__ A, const _Float16* __restrict__ B,
             float* __restrict__ Cout, int M, int N, int K) {
    __shared__ _Float16 As[128*32];
    __shared__ _Float16 Bs[128*32];

    const int nb = N >> 7;
    const int bx = blockIdx.x % nb;
    const int by = blockIdx.x / nb;
    const int m0 = by << 7, n0 = bx << 7;

    const int t    = threadIdx.x;
    const int w    = t >> 6;
    const int lane = t & 63;
    const int r    = lane & 15;
    const int quad = lane >> 4;
    const int wm   = (w >> 1) << 6;
    const int wn   = (w & 1) << 6;

    const int srow = lane >> 2;
    const int scol = (lane & 3) << 3;

    floatx4 acc[4][4];
    #pragma unroll
    for (int i = 0; i < 4; i++)
        #pragma unroll
        for (int j = 0; j < 4; j++)
            acc[i][j] = (floatx4){0.f, 0.f, 0.f, 0.f};

    for (int k0 = 0; k0 < K; k0 += 32) {
        __syncthreads();
        #pragma unroll
        for (int p = 0; p < 2; ++p) {
            const int rbase = p*64 + w*16;
            gld_lds16(&A[(size_t)(m0 + rbase + srow)*K + k0 + scol], &As[rbase*32]);
            gld_lds16(&B[(size_t)(n0 + rbase + srow)*K + k0 + scol], &Bs[rbase*32]);
        }
        __syncthreads();

        half8 af[4], bf[4];
        #pragma unroll
        for (int i = 0; i < 4; i++)
            af[i] = *(const half8*)&As[(wm + i*16 + r)*32 + quad*8];
        #pragma unroll
        for (int j = 0; j < 4; j++)
            bf[j] = *(const half8*)&Bs[(wn + j*16 + r)*32 + quad*8];

        #pragma unroll
        for (int i = 0; i < 4; i++)
            #pragma unroll
            for (int j = 0; j < 4; j++)
                acc[i][j] = __builtin_amdgcn_mfma_f32_16x16x32_f16(
                                af[i], bf[j], acc[i][j], 0, 0, 0);
    }

    #pragma unroll
    for (int i = 0; i < 4; i++)
        #pragma unroll
        for (int j = 0; j < 4; j++)
            #pragma unroll
            for (int v = 0; v < 4; v++) {
                const int m = m0 + wm + i*16 + quad*4 + v;
                const int n = n0 + wn + j*16 + r;
                Cout[(size_t)m*N + n] = acc[i][j][v];
            }
}

// ---------------------------------------------------------------------------
// Fused Q/K/V projection. Grid = 64 m-tiles x 24 n-tiles (wt = n-tile>>3).
// wt 0/1 (Q/K): 3-chain split GEMM, wt 2 (V): 1-chain hi GEMM.
// Epilogue: per-wave LDS transpose (scratch = staging LDS reused, stride 68)
// -> lanes own 8 consecutive d (Q/K: RoPE pairs in-register, b128 hi/lo
// stores) or 8 consecutive s (V: b128 stores into [b][h][d][s]).
// Arithmetic identical to the scalar epilogue (same products, same order).
// ---------------------------------------------------------------------------
__global__ __launch_bounds__(256)
void gemm_qkv(const _Float16* __restrict__ Axh, const _Float16* __restrict__ Axl,
              const _Float16* __restrict__ qwh, const _Float16* __restrict__ qwl,
              const _Float16* __restrict__ kwh, const _Float16* __restrict__ kwl,
              const _Float16* __restrict__ vwh,
              _Float16* __restrict__ Qhi, _Float16* __restrict__ Qlo,
              _Float16* __restrict__ Khi, _Float16* __restrict__ Klo,
              _Float16* __restrict__ Vt,  const float2* __restrict__ tab) {
    __shared__ _Float16 smem[4*4096];      // 32 KB: staging planes / epilogue scratch
    _Float16* Ash = smem;
    _Float16* Asl = smem + 4096;
    _Float16* Bsh = smem + 8192;
    _Float16* Bsl = smem + 12288;

    const int bxa = blockIdx.x;
    const int bx  = bxa % 24;
    const int by  = bxa / 24;
    const int wt  = bx >> 3;               // 0=Q, 1=K, 2=V
    const int n0  = (bx & 7) << 7;         // within this weight's 1024 cols
    const int m0  = by << 7;

    const _Float16* Bh = (wt == 0) ? qwh : (wt == 1) ? kwh : vwh;
    const _Float16* Bl = (wt == 0) ? qwl : kwl;      // unused when wt==2

    const int t    = threadIdx.x;
    const int w    = t >> 6;
    const int lane = t & 63;
    const int r    = lane & 15;
    const int quad = lane >> 4;
    const int wm   = (w >> 1) << 6;
    const int wn   = (w & 1) << 6;

    const int srow = lane >> 2;
    const int scol = (lane & 3) << 3;

    floatx4 acc[4][4];
    #pragma unroll
    for (int i = 0; i < 4; i++)
        #pragma unroll
        for (int j = 0; j < 4; j++)
            acc[i][j] = (floatx4){0.f, 0.f, 0.f, 0.f};

    for (int k0 = 0; k0 < 1024; k0 += 32) {
        __syncthreads();
        #pragma unroll
        for (int p = 0; p < 2; ++p) {
            const int rbase = p*64 + w*16;
            const size_t ga = (size_t)(m0 + rbase + srow)*1024 + k0 + scol;
            const size_t gb = (size_t)(n0 + rbase + srow)*1024 + k0 + scol;
            gld_lds16(&Axh[ga], &Ash[rbase*32]);
            gld_lds16(&Bh [gb], &Bsh[rbase*32]);
            if (wt < 2) {
                gld_lds16(&Axl[ga], &Asl[rbase*32]);
                gld_lds16(&Bl [gb], &Bsl[rbase*32]);
            }
        }
        __syncthreads();

        half8 ah[4], bh[4];
        #pragma unroll
        for (int i = 0; i < 4; i++)
            ah[i] = *(const half8*)&Ash[(wm + i*16 + r)*32 + quad*8];
        #pragma unroll
        for (int j = 0; j < 4; j++)
            bh[j] = *(const half8*)&Bsh[(wn + j*16 + r)*32 + quad*8];

        if (wt < 2) {
            half8 al[4], bl[4];
            #pragma unroll
            for (int i = 0; i < 4; i++)
                al[i] = *(const half8*)&Asl[(wm + i*16 + r)*32 + quad*8];
            #pragma unroll
            for (int j = 0; j < 4; j++)
                bl[j] = *(const half8*)&Bsl[(wn + j*16 + r)*32 + quad*8];
            #pragma unroll
            for (int i = 0; i < 4; i++)
                #pragma unroll
                for (int j = 0; j < 4; j++) {
                    acc[i][j] = __builtin_amdgcn_mfma_f32_16x16x32_f16(
                                    ah[i], bh[j], acc[i][j], 0, 0, 0);
                    acc[i][j] = __builtin_amdgcn_mfma_f32_16x16x32_f16(
                                    ah[i], bl[j], acc[i][j], 0, 0, 0);
                    acc[i][j] = __builtin_amdgcn_mfma_f32_16x16x32_f16(
                                    al[i], bh[j], acc[i][j], 0, 0, 0);
                }
        } else {
            #pragma unroll
            for (int i = 0; i < 4; i++)
                #pragma unroll
                for (int j = 0; j < 4; j++)
                    acc[i][j] = __builtin_amdgcn_mfma_f32_16x16x32_f16(
                                    ah[i], bh[j], acc[i][j], 0, 0, 0);
        }
    }

    // ----- epilogue: per-wave LDS transpose + wide stores -----
    __syncthreads();                       // K-loop LDS reads done; reuse as scratch
    float* sc = (float*)smem + w*1088;     // 16 rows x stride 68 fp32, per wave
    const int g  = lane & 7;               // 8-col group
    const int rw = lane >> 3;              // 0..7
    const int hh = (n0 + wn) >> 6;         // head fixed per wave (n0%128==0, wn 0/64)

    if (wt < 2) {
        _Float16* Chi = wt ? Khi : Qhi;
        _Float16* Clo = wt ? Klo : Qlo;
        #pragma unroll
        for (int i = 0; i < 4; i++) {
            #pragma unroll
            for (int j = 0; j < 4; j++)
                #pragma unroll
                for (int v = 0; v < 4; v++)
                    sc[(quad*4 + v)*68 + j*16 + r] = acc[i][j][v];
            // per-wave region; same-wave DS ops are in-order (Pl pattern)
            #pragma unroll
            for (int rg = 0; rg < 2; rg++) {
                const int row = rw + rg*8;
                const int m   = m0 + wm + i*16 + row;
                const int bb  = m >> 11, s_ = m & 2047;
                const float4 va = *(const float4*)&sc[row*68 + g*8];
                const float4 vb = *(const float4*)&sc[row*68 + g*8 + 4];
                const float vv[8] = {va.x, va.y, va.z, va.w,
                                     vb.x, vb.y, vb.z, vb.w};
                half8 hv, lv;
                #pragma unroll
                for (int p2 = 0; p2 < 4; p2++) {
                    const float2 cs = tab[s_*32 + g*4 + p2];
                    const float e0 = vv[2*p2], o0 = vv[2*p2+1];
                    const float re = e0*cs.x - o0*cs.y;
                    const float ro = e0*cs.y + o0*cs.x;
                    const _Float16 rh = (_Float16)re;
                    const _Float16 oh = (_Float16)ro;
                    hv[2*p2]   = rh; lv[2*p2]   = (_Float16)(re - (float)rh);
                    hv[2*p2+1] = oh; lv[2*p2+1] = (_Float16)(ro - (float)oh);
                }
                const size_t idx = ((((size_t)bb*NUM_HEADS + hh)*SEQ + s_) << 6) + g*8;
                *(half8*)&Chi[idx] = hv;
                *(half8*)&Clo[idx] = lv;
            }
        }
    } else {
        const int d = lane;                // 0..63, col within wave's 64
        #pragma unroll
        for (int i = 0; i < 4; i++) {
            #pragma unroll
            for (int j = 0; j < 4; j++)
                #pragma unroll
                for (int v = 0; v < 4; v++)
                    sc[(quad*4 + v)*68 + j*16 + r] = acc[i][j][v];
            #pragma unroll
            for (int rg = 0; rg < 2; rg++) {
                const int m  = m0 + wm + i*16 + rg*8;
                const int bb = m >> 11, s_ = m & 2047;
                half8 ov;
                #pragma unroll
                for (int rr = 0; rr < 8; rr++)
                    ov[rr] = (_Float16)sc[(rg*8 + rr)*68 + d];
                *(half8*)&Vt[((((size_t)bb*NUM_HEADS + hh)*HEAD_DIM + d) << 11) + s_] = ov;
            }
        }
    }
}

// ---------------------------------------------------------------------------
// Causal flash attention (round-5 configuration — 256 thr, 64 q-rows/block).
// 64-key iterations; K hi/lo and V^T staged as 64x32 half-tiles (64B LDS rows
// -> contiguous-1024B ds_read_b128, conflict-minimal).
// S^T = K·Q^T (q in lane&15 -> softmax reductions are 2 shuffles).
// O^T = V^T·P (q in lane&15 -> alpha rescale shuffle-free).
// Longest blocks launch first (LPT).
// ---------------------------------------------------------------------------
#define PSTR 72   // P strip stride in f16
__global__ __launch_bounds__(256)
void flash_attn(const _Float16* __restrict__ Qhi, const _Float16* __restrict__ Qlo,
                const _Float16* __restrict__ Khi, const _Float16* __restrict__ Klo,
                const _Float16* __restrict__ Vt,  _Float16* __restrict__ AO) {
    __shared__ _Float16 Ksh0[64*32];   // K hi, d [0,32)
    __shared__ _Float16 Ksh1[64*32];   // K hi, d [32,64)
    __shared__ _Float16 Ksl0[64*32];   // K lo, d [0,32)
    __shared__ _Float16 Ksl1[64*32];   // K lo, d [32,64)
    __shared__ _Float16 Vs0 [64*32];   // V^T, keys [0,32)
    __shared__ _Float16 Vs1 [64*32];   // V^T, keys [32,64)
    __shared__ _Float16 Pl  [4][16*PSTR];

    const int t    = threadIdx.x;
    const int w    = t >> 6;
    const int lane = t & 63;
    const int r    = lane & 15;
    const int quad = lane >> 4;

    const int bx = blockIdx.x;
    const int bh = bx & 63;                 // 64 bh, fastest
    const int qb = 31 - (bx >> 6);          // 32 q-blocks, longest first
    const int q0w = qb*64 + w*16;
    const int b  = bh >> 4, h = bh & 15;

    const _Float16* Qh_ = Qhi + (size_t)bh * SEQ * HEAD_DIM;
    const _Float16* Ql_ = Qlo + (size_t)bh * SEQ * HEAD_DIM;
    const _Float16* Khg = Khi + (size_t)bh * SEQ * HEAD_DIM;
    const _Float16* Klg = Klo + (size_t)bh * SEQ * HEAD_DIM;
    const _Float16* Vtg = Vt  + (size_t)bh * HEAD_DIM * SEQ;

    // Q B-fragments: B[n=q=r][k=d=c*32+quad*8+j], hi and lo
    half8 qh[2], ql[2];
    #pragma unroll
    for (int c = 0; c < 2; ++c) {
        qh[c] = *(const half8*)&Qh_[(size_t)(q0w + r)*64 + c*32 + quad*8];
        ql[c] = *(const half8*)&Ql_[(size_t)(q0w + r)*64 + c*32 + quad*8];
    }

    // O^T accumulators: tile d = dt*16+quad*4+v, col q = r
    floatx4 ot[4];
    #pragma unroll
    for (int dt = 0; dt < 4; ++dt) ot[dt] = (floatx4){0.f,0.f,0.f,0.f};
    float mi = -1e30f, li = 0.f;

    const int sr = lane >> 2;             // staging: 16 rows per strip
    const int sc = (lane & 3) << 3;

    const int niter = qb + 1;
    for (int kt = 0; kt < niter; ++kt) {
        const int k0 = kt << 6;

        __syncthreads();                  // prior iter's LDS reads complete
        {
            const int rb  = w << 4;       // wave-uniform strip base (w*16)
            const int row = rb + sr;
            const size_t kr = (size_t)(k0 + row)*64;
            gld_lds16(&Khg[kr +      sc], &Ksh0[rb*32]);
            gld_lds16(&Khg[kr + 32 + sc], &Ksh1[rb*32]);
            gld_lds16(&Klg[kr +      sc], &Ksl0[rb*32]);
            gld_lds16(&Klg[kr + 32 + sc], &Ksl1[rb*32]);
            const size_t vr = (size_t)row*SEQ + k0;
            gld_lds16(&Vtg[vr +      sc], &Vs0[rb*32]);
            gld_lds16(&Vtg[vr + 32 + sc], &Vs1[rb*32]);
        }
        __syncthreads();                  // vmcnt(0): staging complete

        // S^T = K·Q^T : 16 scores per lane (key = sub*16+quad*4+v, q = r)
        float s[16];
        #pragma unroll
        for (int sub = 0; sub < 4; ++sub) {
            floatx4 a = (floatx4){0.f,0.f,0.f,0.f};
            const int fr = (sub*16 + r)*32 + quad*8;   // contiguous 1024B/read
            const half8 kh0 = *(const half8*)&Ksh0[fr];
            const half8 kh1 = *(const half8*)&Ksh1[fr];
            const half8 kl0 = *(const half8*)&Ksl0[fr];
            const half8 kl1 = *(const half8*)&Ksl1[fr];
            a = __builtin_amdgcn_mfma_f32_16x16x32_f16(kh0, qh[0], a, 0, 0, 0);
            a = __builtin_amdgcn_mfma_f32_16x16x32_f16(kh1, qh[1], a, 0, 0, 0);
            a = __builtin_amdgcn_mfma_f32_16x16x32_f16(kh0, ql[0], a, 0, 0, 0);
            a = __builtin_amdgcn_mfma_f32_16x16x32_f16(kh1, ql[1], a, 0, 0, 0);
            a = __builtin_amdgcn_mfma_f32_16x16x32_f16(kl0, qh[0], a, 0, 0, 0);
            a = __builtin_amdgcn_mfma_f32_16x16x32_f16(kl1, qh[1], a, 0, 0, 0);
            #pragma unroll
            for (int v = 0; v < 4; ++v) s[sub*4 + v] = a[v] * 0.125f;
        }

        if (kt == niter - 1) {            // causal mask only in the last tile
            #pragma unroll
            for (int sub = 0; sub < 4; ++sub)
                #pragma unroll
                for (int v = 0; v < 4; ++v)
                    if (k0 + sub*16 + quad*4 + v > q0w + r)
                        s[sub*4 + v] = -1e30f;
        }

        // online softmax over this tile's 64 keys (per lane: q = r)
        float tm = s[0];
        #pragma unroll
        for (int i = 1; i < 16; ++i) tm = fmaxf(tm, s[i]);
        tm = fmaxf(tm, __shfl_xor(tm, 16));
        tm = fmaxf(tm, __shfl_xor(tm, 32));
        const float mn = fmaxf(mi, tm);
        const float alpha = __expf(mi - mn);
        mi = mn;
        float rs = 0.f;
        #pragma unroll
        for (int i = 0; i < 16; ++i) { s[i] = __expf(s[i] - mn); rs += s[i]; }
        rs += __shfl_xor(rs, 16);
        rs += __shfl_xor(rs, 32);
        li = li*alpha + rs;
        #pragma unroll
        for (int dt = 0; dt < 4; ++dt)
            #pragma unroll
            for (int v = 0; v < 4; ++v) ot[dt][v] *= alpha;

        // P^T -> per-wave LDS strip [q=r][key], packed 4-wide
        #pragma unroll
        for (int sub = 0; sub < 4; ++sub) {
            half4v pk = { (_Float16)s[sub*4+0], (_Float16)s[sub*4+1],
                          (_Float16)s[sub*4+2], (_Float16)s[sub*4+3] };
            *(half4v*)&Pl[w][r*PSTR + sub*16 + quad*4] = pk;
        }
        // (same-wave write->read: compiler inserts lgkmcnt wait, no barrier)

        // O^T += V^T·P : A = V^T-frag [m=d][k=key], B = P [n=q][k=key]
        #pragma unroll
        for (int c = 0; c < 2; ++c) {
            const half8 pf = *(const half8*)&Pl[w][r*PSTR + c*32 + quad*8];
            const _Float16* Vsc = c ? Vs1 : Vs0;
            #pragma unroll
            for (int dt = 0; dt < 4; ++dt) {
                const half8 vf = *(const half8*)&Vsc[(dt*16 + r)*32 + quad*8];
                ot[dt] = __builtin_amdgcn_mfma_f32_16x16x32_f16(vf, pf, ot[dt], 0, 0, 0);
            }
        }
    }

    // epilogue: normalize, write AO [b][s=q][h*64 + d] (8B stores)
    const float inv = 1.0f / li;
    const int q = q0w + r;
    #pragma unroll
    for (int dt = 0; dt < 4; ++dt) {
        half4v o = { (_Float16)(ot[dt][0]*inv), (_Float16)(ot[dt][1]*inv),
                     (_Float16)(ot[dt][2]*inv), (_Float16)(ot[dt][3]*inv) };
        *(half4v*)&AO[((size_t)(b*SEQ + q))*D_MODEL + h*HEAD_DIM + dt*16 + quad*4] = o;
    }
}

// ---------------------------------------------------------------------------
extern "C" void kernel_launch(void* const* d_in, const int* in_sizes, int n_in,
                              void* d_out, int out_size, void* d_ws, size_t ws_size,
                              hipStream_t stream) {
    const float* x  = (const float*)d_in[0];
    const float* qw = (const float*)d_in[1];
    const float* kw = (const float*)d_in[2];
    const float* vw = (const float*)d_in[3];
    const float* ow = (const float*)d_in[4];
    float* out = (float*)d_out;

    // workspace layout (_Float16 counts), total ~147.3 MB
    _Float16* xh  = (_Float16*)d_ws;
    _Float16* xl  = xh  + (size_t)MROWS * D_MODEL;
    _Float16* qwh = xl  + (size_t)MROWS * D_MODEL;
    _Float16* qwl = qwh + (size_t)D_MODEL * D_MODEL;
    _Float16* kwh = qwl + (size_t)D_MODEL * D_MODEL;
    _Float16* kwl = kwh + (size_t)D_MODEL * D_MODEL;
    _Float16* vwh = kwl + (size_t)D_MODEL * D_MODEL;
    _Float16* owh = vwh + (size_t)D_MODEL * D_MODEL;
    _Float16* Qhi = owh + (size_t)D_MODEL * D_MODEL;
    _Float16* Qlo = Qhi + (size_t)MROWS * D_MODEL;
    _Float16* Khi = Qlo + (size_t)MROWS * D_MODEL;
    _Float16* Klo = Khi + (size_t)MROWS * D_MODEL;
    _Float16* Vt  = Klo + (size_t)MROWS * D_MODEL;
    _Float16* AO  = Vt  + (size_t)MROWS * D_MODEL;
    float2*   tab = (float2*)(AO + (size_t)MROWS * D_MODEL);

    rope_table<<<(SEQ*32)/256, 256, 0, stream>>>(tab);

    const int nx4 = MROWS * D_MODEL / 4;
    f32_split_f16<<<nx4/256, 256, 0, stream>>>(x, xh, xl, nx4);
    conv_weights<<<(4*262144)/256, 256, 0, stream>>>(qw, kw, vw, ow,
                                                     qwh, qwl, kwh, kwl, vwh, owh);

    gemm_qkv<<<64*24, 256, 0, stream>>>(xh, xl, qwh, qwl, kwh, kwl, vwh,
                                        Qhi, Qlo, Khi, Klo, Vt, tab);

    flash_attn<<<BH * (SEQ/64), 256, 0, stream>>>(Qhi, Qlo, Khi, Klo, Vt, AO);

    gemm_bt<<<(MROWS/128)*(D_MODEL/128), 256, 0, stream>>>(AO, owh, out,
                                                           MROWS, D_MODEL, D_MODEL);
}